// Round 1
// baseline (21159.555 us; speedup 1.0000x reference)
//
#include <hip/hip_runtime.h>

// Pendulum RNN+head: 3-layer LSTM (H=128) over B=256 rows, 512 input steps +
// 512 autoregressive steps. Rows are independent -> persistent kernel,
// 64 blocks x 512 threads, 4 rows/block, no inter-block communication.
// Weights packed to fp16, transposed + gate-interleaved for coalesced
// dwordx4 loads feeding v_dot2_f32_f16 (f32 accumulate).

typedef _Float16 f16;
typedef _Float16 f16x2 __attribute__((ext_vector_type(2)));
typedef unsigned int u32;

#define B_TOT 256
#define T_IN 512
#define T_TOT 1024
#define NROW 4   // rows per block
#define NBLK 64  // B_TOT / NROW

__device__ __forceinline__ f16x2 u2h(u32 u) { return __builtin_bit_cast(f16x2, u); }

__device__ __forceinline__ float fdot2f(f16x2 a, f16x2 b, float c) {
#if __has_builtin(__builtin_amdgcn_fdot2)
  return __builtin_amdgcn_fdot2(a, b, c, false);
#else
  return c + (float)a[0] * (float)b[0] + (float)a[1] * (float)b[1];
#endif
}

__device__ __forceinline__ float frcp(float x) {
#if __has_builtin(__builtin_amdgcn_rcpf)
  return __builtin_amdgcn_rcpf(x);
#else
  return 1.f / x;
#endif
}
__device__ __forceinline__ float fsigm(float x) { return frcp(1.f + __expf(-x)); }
__device__ __forceinline__ float ftanh(float x) { return 1.f - 2.f * frcp(1.f + __expf(2.f * x)); }

// ---- weight packing -------------------------------------------------------
// Gate matrices: dst uint[(p*128 + idx)*4 + g] = half2{ W[g*128+idx][2p], [2p+1] }
// where k runs over A's 128 cols (p<Pa) then B's 128 cols.
__global__ void pack_cat(u32* dst, const float* A, const float* Bm, int Pa, int P) {
  int tid = blockIdx.x * 256 + threadIdx.x;
  if (tid >= P * 512) return;
  int g = tid & 3;
  int idx = (tid >> 2) & 127;
  int p = tid >> 9;
  int j = g * 128 + idx;
  const float* src;
  int k;
  if (p < Pa) { src = A; k = 2 * p; } else { src = Bm; k = 2 * (p - Pa); }
  union { f16 h[2]; u32 u; } cv;
  cv.h[0] = (f16)src[j * 128 + k];
  cv.h[1] = (f16)src[j * 128 + k + 1];
  dst[tid] = cv.u;
}

// 128x128 head matrices: dst uint[p*128 + idx] = half2{ src[idx][2p], src[idx][2p+1] }
__global__ void pack_plain(u32* dst, const float* src) {
  int tid = blockIdx.x * 256 + threadIdx.x;
  if (tid >= 64 * 128) return;
  int idx = tid & 127;
  int p = tid >> 7;
  union { f16 h[2]; u32 u; } cv;
  cv.h[0] = (f16)src[idx * 128 + 2 * p];
  cv.h[1] = (f16)src[idx * 128 + 2 * p + 1];
  dst[tid] = cv.u;
}

__global__ void bias_add3(float* d1, float* d2, float* d3,
                          const float* a1, const float* b1,
                          const float* a2, const float* b2,
                          const float* a3, const float* b3) {
  int tid = blockIdx.x * 256 + threadIdx.x;
  if (tid < 512) d1[tid] = a1[tid] + b1[tid];
  else if (tid < 1024) d2[tid - 512] = a2[tid - 512] + b2[tid - 512];
  else if (tid < 1536) d3[tid - 1024] = a3[tid - 1024] + b3[tid - 1024];
}

// ---- dot helpers ----------------------------------------------------------
// Weight pairs p in [P0,P1); h pairs contiguous starting at hb (pair P0).
// a[0..3] accumulate gates i,f,g,o.
template <int P0, int P1>
__device__ __forceinline__ void gate_dot(const uint4* __restrict__ WT,
                                         const f16* __restrict__ hb,
                                         int idx, float (&a)[4]) {
#pragma unroll 2
  for (int p = P0; p < P1; p += 4) {
    uint4 h4 = *reinterpret_cast<const uint4*>(hb + 2 * (p - P0));
    u32 hp[4] = {h4.x, h4.y, h4.z, h4.w};
#pragma unroll
    for (int q = 0; q < 4; ++q) {
      uint4 w = WT[(p + q) * 128 + idx];
      f16x2 hh = u2h(hp[q]);
      a[0] = fdot2f(u2h(w.x), hh, a[0]);
      a[1] = fdot2f(u2h(w.y), hh, a[1]);
      a[2] = fdot2f(u2h(w.z), hh, a[2]);
      a[3] = fdot2f(u2h(w.w), hh, a[3]);
    }
  }
}

__device__ __forceinline__ float head_dot(const u32* __restrict__ WT,
                                          const f16* __restrict__ hb,
                                          int idx, float acc) {
#pragma unroll 2
  for (int p = 0; p < 64; p += 4) {
    uint4 h4 = *reinterpret_cast<const uint4*>(hb + 2 * p);
    u32 hp[4] = {h4.x, h4.y, h4.z, h4.w};
#pragma unroll
    for (int q = 0; q < 4; ++q)
      acc = fdot2f(u2h(WT[(p + q) * 128 + idx]), u2h(hp[q]), acc);
  }
  return acc;
}

// ---- main persistent kernel ----------------------------------------------
__global__ __launch_bounds__(512) void pendulum_persist(
    const float* __restrict__ input, const float* __restrict__ wih1,
    const float* __restrict__ B1, const float* __restrict__ B2,
    const float* __restrict__ B3, const uint4* __restrict__ WT1,
    const uint4* __restrict__ WT2, const uint4* __restrict__ WT3,
    const u32* __restrict__ WTV, const u32* __restrict__ WTO,
    const float* __restrict__ bv, const float* __restrict__ outb,
    const float* __restrict__ linw, const float* __restrict__ linb,
    float* __restrict__ out) {
  // h stored fp16, double-buffered; per row: [h1(128) h2(128) h3(128)]
  __shared__ __align__(16) f16 hbuf[2][NROW][384];
  __shared__ __align__(16) f16 ubuf[NROW][128];
  __shared__ float xcur[NROW];
  __shared__ float redbuf[8];

  const int t = threadIdx.x;
  const int r = t >> 7;    // row within block (0..3)
  const int idx = t & 127; // hidden index
  const int row = blockIdx.x * NROW + r;

  float b1g[4], b2g[4], b3g[4], w1g[4];
#pragma unroll
  for (int g = 0; g < 4; ++g) {
    b1g[g] = B1[g * 128 + idx];
    b2g[g] = B2[g * 128 + idx];
    b3g[g] = B3[g * 128 + idx];
    w1g[g] = wih1[g * 128 + idx];
  }
  const float bvr = bv[idx], obr = outb[idx], lwr = linw[idx], lb = linb[0];
  float c1 = 0.f, c2 = 0.f, c3 = 0.f;

#pragma unroll
  for (int L = 0; L < 3; ++L) {
    hbuf[0][r][L * 128 + idx] = (f16)0.f;
    hbuf[1][r][L * 128 + idx] = (f16)0.f;
  }
  __syncthreads();

  int s = 0;
  for (int step = 0; step < T_TOT; ++step) {
    float xv = (step < T_IN) ? input[row * T_IN + step] : xcur[r];

    // ---- layer 1: gates = b1 + x*wih1 + h1_old @ Whh1^T
    float a[4];
#pragma unroll
    for (int g = 0; g < 4; ++g) a[g] = b1g[g] + xv * w1g[g];
    gate_dot<0, 64>(WT1, &hbuf[s][r][0], idx, a);
    {
      float i1 = fsigm(a[0]), f1 = fsigm(a[1]), g1 = ftanh(a[2]), o1 = fsigm(a[3]);
      c1 = f1 * c1 + i1 * g1;
      hbuf[s ^ 1][r][idx] = (f16)(o1 * ftanh(c1));
    }
    __syncthreads(); // h1_new visible

    // ---- layer 2: [h1_new | h2_old] @ [Wih2|Whh2]^T
#pragma unroll
    for (int g = 0; g < 4; ++g) a[g] = b2g[g];
    gate_dot<0, 64>(WT2, &hbuf[s ^ 1][r][0], idx, a);
    gate_dot<64, 128>(WT2, &hbuf[s][r][128], idx, a);
    {
      float i2 = fsigm(a[0]), f2 = fsigm(a[1]), g2 = ftanh(a[2]), o2 = fsigm(a[3]);
      c2 = f2 * c2 + i2 * g2;
      hbuf[s ^ 1][r][128 + idx] = (f16)(o2 * ftanh(c2));
    }
    __syncthreads(); // h2_new visible

    // ---- layer 3: [h2_new | h3_old]
#pragma unroll
    for (int g = 0; g < 4; ++g) a[g] = b3g[g];
    gate_dot<0, 64>(WT3, &hbuf[s ^ 1][r][128], idx, a);
    gate_dot<64, 128>(WT3, &hbuf[s][r][256], idx, a);
    {
      float i3 = fsigm(a[0]), f3 = fsigm(a[1]), g3 = ftanh(a[2]), o3 = fsigm(a[3]);
      c3 = f3 * c3 + i3 * g3;
      hbuf[s ^ 1][r][256 + idx] = (f16)(o3 * ftanh(c3));
    }
    __syncthreads(); // h3_new visible

    // ---- head: u = Wv h3 + bv ; attn = out_w u + out_b ; y = lin_w.attn + lin_b
    float uv = bvr + head_dot(WTV, &hbuf[s ^ 1][r][256], idx, 0.f);
    ubuf[r][idx] = (f16)uv;
    __syncthreads(); // u visible

    float at = obr + head_dot(WTO, &ubuf[r][0], idx, 0.f);
    float v = at * lwr;
#pragma unroll
    for (int k = 32; k; k >>= 1) v += __shfl_xor(v, k, 64);
    if ((t & 63) == 0) redbuf[t >> 6] = v;
    __syncthreads(); // partials visible
    if (idx == 0) {
      float o = redbuf[2 * r] + redbuf[2 * r + 1] + lb;
      xcur[r] = o;
      out[row * T_TOT + step] = o;
    }
    __syncthreads(); // xcur visible for next step
    s ^= 1;
  }
}

// ---- launch ---------------------------------------------------------------
extern "C" void kernel_launch(void* const* d_in, const int* in_sizes, int n_in,
                              void* d_out, int out_size, void* d_ws, size_t ws_size,
                              hipStream_t stream) {
  const float* input = (const float*)d_in[0];
  // d_in[1] = future (fixed 512, derivable from sizes)
  const float* Wih1 = (const float*)d_in[2];
  const float* Whh1 = (const float*)d_in[3];
  const float* bih1 = (const float*)d_in[4];
  const float* bhh1 = (const float*)d_in[5];
  const float* Wih2 = (const float*)d_in[6];
  const float* Whh2 = (const float*)d_in[7];
  const float* bih2 = (const float*)d_in[8];
  const float* bhh2 = (const float*)d_in[9];
  const float* Wih3 = (const float*)d_in[10];
  const float* Whh3 = (const float*)d_in[11];
  const float* bih3 = (const float*)d_in[12];
  const float* bhh3 = (const float*)d_in[13];
  const float* in_proj_w = (const float*)d_in[14];
  const float* in_proj_b = (const float*)d_in[15];
  const float* out_w = (const float*)d_in[16];
  const float* out_b = (const float*)d_in[17];
  const float* lin_w = (const float*)d_in[18];
  const float* lin_b = (const float*)d_in[19];

  char* ws = (char*)d_ws;
  u32* WT1 = (u32*)(ws + (0 << 10));    // 128 KB
  u32* WT2 = (u32*)(ws + (128 << 10));  // 256 KB
  u32* WT3 = (u32*)(ws + (384 << 10));  // 256 KB
  u32* WTV = (u32*)(ws + (640 << 10));  // 32 KB
  u32* WTO = (u32*)(ws + (672 << 10));  // 32 KB
  float* B1 = (float*)(ws + (704 << 10));
  float* B2 = (float*)(ws + (706 << 10));
  float* B3 = (float*)(ws + (708 << 10));

  pack_cat<<<128, 256, 0, stream>>>(WT1, Whh1, Whh1, 64, 64);
  pack_cat<<<256, 256, 0, stream>>>(WT2, Wih2, Whh2, 64, 128);
  pack_cat<<<256, 256, 0, stream>>>(WT3, Wih3, Whh3, 64, 128);
  pack_plain<<<32, 256, 0, stream>>>(WTV, in_proj_w + 256 * 128);
  pack_plain<<<32, 256, 0, stream>>>(WTO, out_w);
  bias_add3<<<6, 256, 0, stream>>>(B1, B2, B3, bih1, bhh1, bih2, bhh2, bih3, bhh3);

  pendulum_persist<<<NBLK, 512, 0, stream>>>(
      input, Wih1, B1, B2, B3, (const uint4*)WT1, (const uint4*)WT2,
      (const uint4*)WT3, WTV, WTO, in_proj_b + 256, out_b, lin_w, lin_b,
      (float*)d_out);
}